// Round 13
// baseline (171.739 us; speedup 1.0000x reference)
//
#include <hip/hip_runtime.h>

// FNO spectral conv: B=4, CI=CO=32, N=64^3, M=16^3 modes, 4 corners.
// 5-kernel truncated-DFT pipeline:
//   k_f23: x -> B1[plane=bci*64+x1][k2i][k3]  (rfft x3 in REGISTERS (radix-4,
//          literal twiddles) -> LDS swizzled -> DFT x2: radix-2 E/O fold +
//          PQRS conj-pair; stage-2 fully unrolled -> immediate-offset tw reads)
//   k_f1 : B1 -> C[bci][k1i][k2i][k3]         (DFT x1, radix-2 fold + PQRS)
//   k_mix: C -> D                             (per-mode 32x32 cplx channel mix)
//   k_i1 : D -> B2[bco][x1][k2i][k3]          (inverse x1, 4-way phase-class
//          fold: G_c sums + i^cq combine, 36 fma/output vs 64)
//   k_i23: B2 -> out                          (inverse x2 (same 4-way fold) +
//          irfft x3, 2 planes/blk)
// mode index convention: i in [0,16) -> mode i ; [16,32) -> mode i+32.
// NOTE: no runtime-indexed __constant__ in hot loops (R5 post-mortem).

#define TWOPI_64 0.0981747704246810387f  // 2*pi/64

// cos/sin(2*pi*i/64) magnitudes
#define M01 0.99518473f
#define M02 0.98078528f
#define M03 0.95694034f
#define M04 0.92387953f
#define M05 0.88192126f
#define M06 0.83146961f
#define M07 0.77301045f
#define M08 0.70710678f
#define M09 0.63439328f
#define M10 0.55557023f
#define M11 0.47139674f
#define M12 0.38268343f
#define M13 0.29028468f
#define M14 0.19509032f
#define M15 0.09801714f

// compile-time tables (folded to literals in fully-unrolled k_f23 stage 1)
constexpr float TC_H[64] = {
  1.0f, M01, M02, M03, M04, M05, M06, M07, M08, M09, M10, M11, M12, M13, M14, M15,
  0.0f, -M15, -M14, -M13, -M12, -M11, -M10, -M09, -M08, -M07, -M06, -M05, -M04, -M03, -M02, -M01,
  -1.0f, -M01, -M02, -M03, -M04, -M05, -M06, -M07, -M08, -M09, -M10, -M11, -M12, -M13, -M14, -M15,
  0.0f, M15, M14, M13, M12, M11, M10, M09, M08, M07, M06, M05, M04, M03, M02, M01};
constexpr float TS_H[64] = {
  0.0f, M15, M14, M13, M12, M11, M10, M09, M08, M07, M06, M05, M04, M03, M02, M01,
  1.0f, M01, M02, M03, M04, M05, M06, M07, M08, M09, M10, M11, M12, M13, M14, M15,
  0.0f, -M15, -M14, -M13, -M12, -M11, -M10, -M09, -M08, -M07, -M06, -M05, -M04, -M03, -M02, -M01,
  -1.0f, -M01, -M02, -M03, -M04, -M05, -M06, -M07, -M08, -M09, -M10, -M11, -M12, -M13, -M14, -M15};

__device__ __forceinline__ void init_tw2(float2* tw, int t) {
  if (t < 64) {
    float s, c;
    sincosf(TWOPI_64 * (float)t, &s, &c);
    tw[t] = make_float2(c, s);
  }
}

// ============================ F23 ============================
// 256 thr = 4 waves; wave w owns plane = blockIdx*4 + w. Per-wave LDS slice.
__global__ __launch_bounds__(256) void k_f23(const float* __restrict__ x,
                                             float2* __restrict__ o) {
  __shared__ float2 Xs[4][1024];  // [wave][x2*16 + swizzled chunk*2 + sub]
  __shared__ float2 tw[64];
  const int t = threadIdx.x;
  const int lane = t & 63;
  const int w = t >> 6;
  const int plane = (blockIdx.x << 2) + w;
  init_tw2(tw, t);

  // ---- stage 1: real DFT x3 -> k3 in [0,16), all in registers ----
  const float4* xg = (const float4*)(x + (size_t)plane * 4096 + lane * 64);
  float r[64];
#pragma unroll
  for (int j = 0; j < 16; ++j) {
    float4 v = xg[j];
    r[4 * j] = v.x; r[4 * j + 1] = v.y; r[4 * j + 2] = v.z; r[4 * j + 3] = v.w;
  }
  // radix-4 pre-pass (x3 = 16a + b)
  float y0[16], y2[16], o0[16], o1[16];
#pragma unroll
  for (int b = 0; b < 16; ++b) {
    float d0 = r[b], d1 = r[16 + b], d2 = r[32 + b], d3 = r[48 + b];
    float e0 = d0 + d2, e1 = d1 + d3;
    o0[b] = d0 - d2; o1[b] = d1 - d3;
    y0[b] = e0 + e1; y2[b] = e0 - e1;
  }
  float4* Xw4 = (float4*)&Xs[w][lane * 16];  // lane's row, 8 16B chunks
#pragma unroll
  for (int c8 = 0; c8 < 8; ++c8) {
    const int k0 = 2 * c8, k1 = 2 * c8 + 1;  // k0 even, k1 odd
    float re0, im0, re1, im1;
    if ((k0 & 3) == 0) {
      re0 = y0[0]; im0 = 0.f;
#pragma unroll
      for (int b = 1; b < 16; ++b) {
        re0 = fmaf(y0[b], TC_H[(k0 * b) & 63], re0);
        im0 = fmaf(-y0[b], TS_H[(k0 * b) & 63], im0);
      }
    } else {
      re0 = y2[0]; im0 = 0.f;
#pragma unroll
      for (int b = 1; b < 16; ++b) {
        re0 = fmaf(y2[b], TC_H[(k0 * b) & 63], re0);
        im0 = fmaf(-y2[b], TS_H[(k0 * b) & 63], im0);
      }
    }
    if ((k1 & 3) == 1) {
      re1 = o0[0]; im1 = -o1[0];
#pragma unroll
      for (int b = 1; b < 16; ++b) {
        float c = TC_H[(k1 * b) & 63], s = TS_H[(k1 * b) & 63];
        re1 = fmaf(o0[b], c, re1); re1 = fmaf(-o1[b], s, re1);
        im1 = fmaf(-o0[b], s, im1); im1 = fmaf(-o1[b], c, im1);
      }
    } else {
      re1 = o0[0]; im1 = o1[0];
#pragma unroll
      for (int b = 1; b < 16; ++b) {
        float c = TC_H[(k1 * b) & 63], s = TS_H[(k1 * b) & 63];
        re1 = fmaf(o0[b], c, re1); re1 = fmaf(o1[b], s, re1);
        im1 = fmaf(o1[b], c, im1); im1 = fmaf(-o0[b], s, im1);
      }
    }
    Xw4[c8 ^ (lane & 7)] = make_float4(re0, im0, re1, im1);  // swizzled chunk
  }
  __syncthreads();  // tw table + own-wave LDS visibility

  // ---- stage 2: complex DFT x2 -> 32 modes ----
  // Radix-2 fold: B(k) = sum_{b<32} w(kb) [X(b) + (-1)^k X(b+32)].
  // FULL unroll: idx[j] become compile-time-known per iteration -> tw reads
  // get immediate offsets, index-update VALU removed.
  const int k3 = lane & 15, g = lane >> 4;
  float P[4] = {0, 0, 0, 0}, Q[4] = {0, 0, 0, 0};
  float R[4] = {0, 0, 0, 0}, S[4] = {0, 0, 0, 0};
  float A0 = 0.f, B0 = 0.f;
  const float ps = (g & 1) ? -1.f : 1.f;
  int kk[4], idx[4];
#pragma unroll
  for (int j = 0; j < 4; ++j) {
    int s = g + 4 * j;
    kk[j] = (s == 0) ? 48 : s;   // slot 0 handles mode 48 (even, ps=+1 ok)
    idx[j] = 0;
  }
  const float2* row = &Xs[w][0];
  const int sub = k3 & 1, ch = k3 >> 1;
#pragma unroll
  for (int b = 0; b < 32; ++b) {
    const int off = ((ch ^ (b & 7)) << 1) + sub;  // (b+32)&7 == b&7: same off
    float2 v1 = row[b * 16 + off];
    float2 v2 = row[(b + 32) * 16 + off];
    float2 par = make_float2(fmaf(ps, v2.x, v1.x), fmaf(ps, v2.y, v1.y));
#pragma unroll
    for (int j = 0; j < 4; ++j) {
      float2 wv = tw[idx[j]];
      idx[j] = (idx[j] + kk[j]) & 63;
      P[j] = fmaf(par.x, wv.x, P[j]); Q[j] = fmaf(par.y, wv.y, Q[j]);
      R[j] = fmaf(par.y, wv.x, R[j]); S[j] = fmaf(par.x, wv.y, S[j]);
    }
    A0 += par.x; B0 += par.y;  // g=0 (E-fold): mode 0 = sum_b E(b)
  }
  float2* ob = o + (size_t)plane * 512 + k3;
#pragma unroll
  for (int j = 0; j < 4; ++j) {
    int s = g + 4 * j;
    float2 oa = make_float2(P[j] + Q[j], R[j] - S[j]);
    if (s == 0) {
      ob[256] = oa;                    // mode 48 -> k2i=16
      ob[0] = make_float2(A0, B0);     // mode 0  -> k2i=0
    } else {
      ob[s * 16] = oa;                              // mode s -> k2i=s
      ob[(32 - s) * 16] = make_float2(P[j] - Q[j], R[j] + S[j]);  // 64-s
    }
  }
}

// ============================ F1 ============================
// per (bci,k2i). 512 thr. Radix-2 fold over x1 + PQRS conj-pair, k3-paired.
__global__ __launch_bounds__(512) void k_f1(const float2* __restrict__ in,
                                            float2* __restrict__ o) {
  __shared__ float2 xsf[64 * 18];
  __shared__ float4 red[2][512];
  __shared__ float4 redAB[32];
  __shared__ float2 tw[64];
  const int t = threadIdx.x;
  init_tw2(tw, t);
  const int bci = blockIdx.x >> 5, k2i = blockIdx.x & 31;
  {
    int x1 = t >> 3, k3p = t & 7;
    float4 v = ((const float4*)in)[((size_t)(bci * 64 + x1) * 32 + k2i) * 8 + k3p];
    *(float4*)&xsf[x1 * 18 + 2 * k3p] = v;
  }
  __syncthreads();
  {
    const int k3p = t & 7, slot = (t >> 3) & 15, h = t >> 7;  // h in [0,4)
    const bool isz = (slot == 0);
    const int kk = isz ? 48 : slot;
    const float ps = (slot & 1) ? -1.f : 1.f;  // slot0: kk=48 even, ps=+1 ok
    float Pa=0,Qa=0,Ra=0,Sa=0, Pb=0,Qb=0,Rb=0,Sb=0, Aa=0,Ba=0,Ab=0,Bb=0;
    int idx = (kk * 8 * h) & 63;
#pragma unroll
    for (int i = 0; i < 8; ++i) {
      int b = 8 * h + i;  // b in [0,32): fold (b, b+32)
      float4 v1 = *(const float4*)&xsf[b * 18 + 2 * k3p];
      float4 v2 = *(const float4*)&xsf[(b + 32) * 18 + 2 * k3p];
      float4 par;
      par.x = fmaf(ps, v2.x, v1.x); par.y = fmaf(ps, v2.y, v1.y);
      par.z = fmaf(ps, v2.z, v1.z); par.w = fmaf(ps, v2.w, v1.w);
      float2 w = tw[idx]; idx = (idx + kk) & 63;
      Pa = fmaf(par.x, w.x, Pa); Qa = fmaf(par.y, w.y, Qa);
      Ra = fmaf(par.y, w.x, Ra); Sa = fmaf(par.x, w.y, Sa);
      Pb = fmaf(par.z, w.x, Pb); Qb = fmaf(par.w, w.y, Qb);
      Rb = fmaf(par.w, w.x, Rb); Sb = fmaf(par.z, w.y, Sb);
      if (isz) { Aa += par.x; Ba += par.y; Ab += par.z; Bb += par.w; }
    }
    red[0][k3p + 8 * slot + 128 * h] = make_float4(Pa, Qa, Ra, Sa);
    red[1][k3p + 8 * slot + 128 * h] = make_float4(Pb, Qb, Rb, Sb);
    if (isz) redAB[8 * h + k3p] = make_float4(Aa, Ba, Ab, Bb);
  }
  __syncthreads();
  if (t < 256) {
    const int slot = t >> 4, k3 = t & 15, k3p = k3 >> 1, half = k3 & 1;
    int b = k3p + 8 * slot;
    float4 s0 = red[half][b], s1 = red[half][b + 128];
    float4 s2 = red[half][b + 256], s3 = red[half][b + 384];
    float P = s0.x + s1.x + s2.x + s3.x, Q = s0.y + s1.y + s2.y + s3.y;
    float R = s0.z + s1.z + s2.z + s3.z, S = s0.w + s1.w + s2.w + s3.w;
    float2 oa = make_float2(P + Q, R - S);
    float2 ob; int ka, kb;
    if (slot == 0) {
      ka = 16; kb = 0;
      const float2* ab = (const float2*)redAB;
      float2 z0 = ab[(0 * 8 + k3p) * 2 + half], z1 = ab[(1 * 8 + k3p) * 2 + half];
      float2 z2 = ab[(2 * 8 + k3p) * 2 + half], z3 = ab[(3 * 8 + k3p) * 2 + half];
      ob = make_float2(z0.x + z1.x + z2.x + z3.x, z0.y + z1.y + z2.y + z3.y);
    } else {
      ka = slot; kb = 32 - slot;
      ob = make_float2(P - Q, R + S);
    }
    o[(((size_t)bci * 32 + ka) * 32 + k2i) * 16 + k3] = oa;
    o[(((size_t)bci * 32 + kb) * 32 + k2i) * 16 + k3] = ob;
  }
}

// ============================ MIX ============================
__global__ __launch_bounds__(512) void k_mix(const float2* __restrict__ X,
                                             const float2* __restrict__ w0,
                                             const float2* __restrict__ w1,
                                             const float2* __restrict__ w2,
                                             const float2* __restrict__ w3,
                                             float2* __restrict__ Y) {
  __shared__ float2 xs[2048];  // [b*32+ci][k3]
  const int t = threadIdx.x;
  const int k1i = blockIdx.x >> 5, k2i = blockIdx.x & 31;
  const float2* w = (k1i < 16) ? ((k2i < 16) ? w0 : w1) : ((k2i < 16) ? w2 : w3);
  const int a = k1i & 15, bb = k2i & 15;
  for (int q = t; q < 2048; q += 512) {
    int bci = q >> 4, k3 = q & 15;
    xs[q] = X[((size_t)bci * 1024 + blockIdx.x) * 16 + k3];
  }
  __syncthreads();
  const int k3 = t & 15, co = t >> 4;
  float2 a0 = {0, 0}, a1 = {0, 0}, a2 = {0, 0}, a3 = {0, 0};
  const float2* wp = w + (size_t)co * 4096 + a * 256 + bb * 16 + k3;
#pragma unroll 16
  for (int ci = 0; ci < 32; ++ci) {
    float2 wv = wp[(size_t)ci * 131072];
    float2 x0 = xs[(0 * 32 + ci) * 16 + k3];
    float2 x1 = xs[(1 * 32 + ci) * 16 + k3];
    float2 x2 = xs[(2 * 32 + ci) * 16 + k3];
    float2 x3 = xs[(3 * 32 + ci) * 16 + k3];
    a0.x = fmaf(x0.x, wv.x, a0.x); a0.x = fmaf(-x0.y, wv.y, a0.x);
    a0.y = fmaf(x0.x, wv.y, a0.y); a0.y = fmaf(x0.y, wv.x, a0.y);
    a1.x = fmaf(x1.x, wv.x, a1.x); a1.x = fmaf(-x1.y, wv.y, a1.x);
    a1.y = fmaf(x1.x, wv.y, a1.y); a1.y = fmaf(x1.y, wv.x, a1.y);
    a2.x = fmaf(x2.x, wv.x, a2.x); a2.x = fmaf(-x2.y, wv.y, a2.x);
    a2.y = fmaf(x2.x, wv.y, a2.y); a2.y = fmaf(x2.y, wv.x, a2.y);
    a3.x = fmaf(x3.x, wv.x, a3.x); a3.x = fmaf(-x3.y, wv.y, a3.x);
    a3.y = fmaf(x3.x, wv.y, a3.y); a3.y = fmaf(x3.y, wv.x, a3.y);
  }
  const float nrm = 1.0f / 262144.0f;  // 1/64^3
  Y[((size_t)(0 * 32 + co) * 1024 + blockIdx.x) * 16 + k3] = make_float2(a0.x * nrm, a0.y * nrm);
  Y[((size_t)(1 * 32 + co) * 1024 + blockIdx.x) * 16 + k3] = make_float2(a1.x * nrm, a1.y * nrm);
  Y[((size_t)(2 * 32 + co) * 1024 + blockIdx.x) * 16 + k3] = make_float2(a2.x * nrm, a2.y * nrm);
  Y[((size_t)(3 * 32 + co) * 1024 + blockIdx.x) * 16 + k3] = make_float2(a3.x * nrm, a3.y * nrm);
}

// ============================ I1 ============================
// per (bco,k2i). 256 thr: k3 = t&15, x1 = t>>4 in [0,16).
// 4-way phase-class fold: G_c = sum_{i==c mod 4} z_i w+(k_i x1);
// out(x1+16q) = sum_c i^{cq} G_c.
__global__ __launch_bounds__(256) void k_i1(const float2* __restrict__ Y,
                                            float2* __restrict__ o) {
  __shared__ float2 zs[32 * 18];
  __shared__ float2 tw[64];
  const int t = threadIdx.x;
  init_tw2(tw, t);
  const int bco = blockIdx.x >> 5, k2i = blockIdx.x & 31;
  {
    int k1i = t >> 3, k3p = t & 7;
    float4 v = ((const float4*)Y)[((size_t)(bco * 32 + k1i) * 32 + k2i) * 8 + k3p];
    *(float4*)&zs[k1i * 18 + 2 * k3p] = v;
  }
  __syncthreads();
  const int k3 = t & 15, x1 = t >> 4;  // x1 in [0,16)
  float Gr[4] = {0, 0, 0, 0}, Gi[4] = {0, 0, 0, 0};
#pragma unroll
  for (int i = 0; i < 32; ++i) {
    const int k = i + ((i >= 16) ? 32 : 0);  // compile-time
    const int c = i & 3;
    float2 z = zs[i * 18 + k3];
    float2 w = tw[(k * x1) & 63];
    Gr[c] = fmaf(z.x, w.x, Gr[c]); Gr[c] = fmaf(-z.y, w.y, Gr[c]);
    Gi[c] = fmaf(z.y, w.x, Gi[c]); Gi[c] = fmaf(z.x, w.y, Gi[c]);
  }
  const float Ar = Gr[0] + Gr[2], Ai = Gi[0] + Gi[2];
  const float Br = Gr[1] + Gr[3], Bi = Gi[1] + Gi[3];
  const float Cr = Gr[0] - Gr[2], Ci = Gi[0] - Gi[2];
  const float Dr = Gr[1] - Gr[3], Di = Gi[1] - Gi[3];
  const size_t base = ((size_t)(bco * 64 + x1) * 32 + k2i) * 16 + k3;
  const size_t st = (size_t)16 * 512;  // x1 += 16
  o[base]          = make_float2(Ar + Br, Ai + Bi);  // q=0
  o[base + st]     = make_float2(Cr - Di, Ci + Dr);  // q=1: C + iD
  o[base + 2 * st] = make_float2(Ar - Br, Ai - Bi);  // q=2
  o[base + 3 * st] = make_float2(Cr + Di, Ci - Dr);  // q=3: C - iD
}

// ============================ I23 ============================
// TWO planes per 512-thr block: half hp = t>>8 owns plane blockIdx*2+hp.
// Stage A (256 thr/plane): inverse k2->x2 via 4-way phase-class fold
// (x2 in [0,16), k3 in [0,16); out(x2+16q) = sum_c i^cq G_c).
// Stage B (256 thr/plane): irfft k3->x3, 4-way x3 tiling via i^k trick.
__global__ __launch_bounds__(512) void k_i23(const float2* __restrict__ Z1,
                                             float* __restrict__ out) {
  __shared__ float2 zs[2][32 * 18];  // [plane][k2i][k3] pad-18
  __shared__ float2 Zc[2][64 * 18];  // [plane][x2][k3] pad-18, Hermitian 2x
  __shared__ float2 tw[64];
  const int t = threadIdx.x;
  init_tw2(tw, t);
  const int hp = t >> 8;       // which plane of the pair
  const int u = t & 255;       // index within the half
  const size_t plane = (size_t)blockIdx.x * 2 + hp;
  {
    int k2i = u >> 3, k3p = u & 7;
    float4 v = ((const float4*)(Z1 + plane * 512))[u];
    *(float4*)&zs[hp][k2i * 18 + 2 * k3p] = v;
  }
  __syncthreads();
  {  // stage A: 4-way phase-class inverse DFT k2 -> x2
    const int k3 = u & 15, x2 = u >> 4;  // x2 in [0,16)
    float Gr[4] = {0, 0, 0, 0}, Gi[4] = {0, 0, 0, 0};
#pragma unroll
    for (int i = 0; i < 32; ++i) {
      const int k = i + ((i >= 16) ? 32 : 0);  // compile-time
      const int c = i & 3;
      float2 z = zs[hp][i * 18 + k3];
      float2 w = tw[(k * x2) & 63];
      Gr[c] = fmaf(z.x, w.x, Gr[c]); Gr[c] = fmaf(-z.y, w.y, Gr[c]);
      Gi[c] = fmaf(z.y, w.x, Gi[c]); Gi[c] = fmaf(z.x, w.y, Gi[c]);
    }
    const float Ar = Gr[0] + Gr[2], Ai = Gi[0] + Gi[2];
    const float Br = Gr[1] + Gr[3], Bi = Gi[1] + Gi[3];
    const float Cr = Gr[0] - Gr[2], Ci = Gi[0] - Gi[2];
    const float Dr = Gr[1] - Gr[3], Di = Gi[1] - Gi[3];
    const float sc = (k3 == 0) ? 1.f : 2.f;  // Hermitian double-count, k3>0
    Zc[hp][(x2)*18 + k3]      = make_float2(sc * (Ar + Br), sc * (Ai + Bi));
    Zc[hp][(x2 + 16)*18 + k3] = make_float2(sc * (Cr - Di), sc * (Ci + Dr));
    Zc[hp][(x2 + 32)*18 + k3] = make_float2(sc * (Ar - Br), sc * (Ai - Bi));
    Zc[hp][(x2 + 48)*18 + k3] = make_float2(sc * (Cr + Di), sc * (Ci - Dr));
  }
  __syncthreads();
  // stage B: out(x3b+16m) = sum_k Re(z_k w(k*x3b) i^{km}); 4 x2-rows/thread
  {
    const int x3b = u & 15, x2g = u >> 4;  // x2g in [0,16)
    float2 wk[16];
    int idx = 0;
#pragma unroll
    for (int k = 0; k < 16; ++k) { wk[k] = tw[idx]; idx = (idx + x3b) & 63; }
    float* ob = out + plane * 4096;
#pragma unroll
    for (int rr = 0; rr < 4; ++rr) {
      int x2 = x2g + 16 * rr;
      const float4* zp = (const float4*)&Zc[hp][x2 * 18];
      float Sa0=0, Sa1=0, Sa2=0, Sa3=0, Sb1=0, Sb3=0;
#pragma unroll
      for (int j = 0; j < 8; ++j) {
        float4 z = zp[j];  // cplx 2j (x,y) and 2j+1 (z,w)
        float2 we = wk[2 * j], wo = wk[2 * j + 1];
        if ((j & 1) == 0) {
          Sa0 = fmaf(z.x, we.x, Sa0); Sa0 = fmaf(-z.y, we.y, Sa0);
          Sa1 = fmaf(z.z, wo.x, Sa1); Sa1 = fmaf(-z.w, wo.y, Sa1);
          Sb1 = fmaf(z.z, wo.y, Sb1); Sb1 = fmaf(z.w, wo.x, Sb1);
        } else {
          Sa2 = fmaf(z.x, we.x, Sa2); Sa2 = fmaf(-z.y, we.y, Sa2);
          Sa3 = fmaf(z.z, wo.x, Sa3); Sa3 = fmaf(-z.w, wo.y, Sa3);
          Sb3 = fmaf(z.z, wo.y, Sb3); Sb3 = fmaf(z.w, wo.x, Sb3);
        }
      }
      ob[x2 * 64 + x3b]      = Sa0 + Sa1 + Sa2 + Sa3;
      ob[x2 * 64 + x3b + 16] = Sa0 - Sb1 - Sa2 + Sb3;
      ob[x2 * 64 + x3b + 32] = Sa0 - Sa1 + Sa2 - Sa3;
      ob[x2 * 64 + x3b + 48] = Sa0 + Sb1 - Sa2 - Sb3;
    }
  }
}

extern "C" void kernel_launch(void* const* d_in, const int* in_sizes, int n_in,
                              void* d_out, int out_size, void* d_ws, size_t ws_size,
                              hipStream_t stream) {
  (void)in_sizes; (void)n_in; (void)out_size; (void)ws_size;
  const float* x = (const float*)d_in[0];
  const float2* w0 = (const float2*)d_in[1];
  const float2* w1 = (const float2*)d_in[2];
  const float2* w2 = (const float2*)d_in[3];
  const float2* w3 = (const float2*)d_in[4];
  float* out = (float*)d_out;
  char* ws = (char*)d_ws;

  // Workspace (67,108,864 B):
  //  B1 = ws[0 : 33.5MB)    f23 out; dead after f1 -> reused as B2 (i1 out)
  //  C  = ws[33.5 : 50.3MB) f1 out
  //  D  = ws[50.3 : 67.1MB) mix out
  float2* B1 = (float2*)ws;
  float2* C  = (float2*)(ws + 33554432);
  float2* D  = (float2*)(ws + 50331648);
  float2* B2 = B1;

  k_f23<<<2048, 256, 0, stream>>>(x, B1);
  k_f1 <<<4096, 512, 0, stream>>>(B1, C);
  k_mix<<<1024, 512, 0, stream>>>(C, w0, w1, w2, w3, D);
  k_i1 <<<4096, 256, 0, stream>>>(D, B2);
  k_i23<<<4096, 512, 0, stream>>>(B2, out);
}

// Round 14
// 143.489 us; speedup vs baseline: 1.1969x; 1.1969x over previous
//
#include <hip/hip_runtime.h>

// FNO spectral conv: B=4, CI=CO=32, N=64^3, M=16^3 modes, 4 corners.
// 5-kernel truncated-DFT pipeline:
//   k_f23: x -> B1[plane=bci*64+x1][k2i][k3]  (rfft x3 in REGISTERS (radix-4,
//          literal twiddles) -> LDS swizzled -> DFT x2: radix-2 E/O fold +
//          PQRS conj-pair; stage-2 unroll 8 — FULL unroll blew VGPR to 136,
//          occupancy 10% (R13 post-mortem) — keep partial unroll)
//   k_f1 : B1 -> C[bci][k1i][k2i][k3]         (DFT x1, radix-2 fold + PQRS)
//   k_mix: C -> D                             (per-mode 32x32 cplx channel mix)
//   k_i1 : D -> B2[bco][x1][k2i][k3]          (inverse x1, 4-way phase-class
//          fold: G_c sums + i^cq combine, 36 fma/output vs 64)
//   k_i23: B2 -> out                          (inverse x2 (same 4-way fold) +
//          irfft x3, 2 planes/blk)
// mode index convention: i in [0,16) -> mode i ; [16,32) -> mode i+32.
// NOTE: no runtime-indexed __constant__ in hot loops (R5 post-mortem).

#define TWOPI_64 0.0981747704246810387f  // 2*pi/64

// cos/sin(2*pi*i/64) magnitudes
#define M01 0.99518473f
#define M02 0.98078528f
#define M03 0.95694034f
#define M04 0.92387953f
#define M05 0.88192126f
#define M06 0.83146961f
#define M07 0.77301045f
#define M08 0.70710678f
#define M09 0.63439328f
#define M10 0.55557023f
#define M11 0.47139674f
#define M12 0.38268343f
#define M13 0.29028468f
#define M14 0.19509032f
#define M15 0.09801714f

// compile-time tables (folded to literals in fully-unrolled k_f23 stage 1)
constexpr float TC_H[64] = {
  1.0f, M01, M02, M03, M04, M05, M06, M07, M08, M09, M10, M11, M12, M13, M14, M15,
  0.0f, -M15, -M14, -M13, -M12, -M11, -M10, -M09, -M08, -M07, -M06, -M05, -M04, -M03, -M02, -M01,
  -1.0f, -M01, -M02, -M03, -M04, -M05, -M06, -M07, -M08, -M09, -M10, -M11, -M12, -M13, -M14, -M15,
  0.0f, M15, M14, M13, M12, M11, M10, M09, M08, M07, M06, M05, M04, M03, M02, M01};
constexpr float TS_H[64] = {
  0.0f, M15, M14, M13, M12, M11, M10, M09, M08, M07, M06, M05, M04, M03, M02, M01,
  1.0f, M01, M02, M03, M04, M05, M06, M07, M08, M09, M10, M11, M12, M13, M14, M15,
  0.0f, -M15, -M14, -M13, -M12, -M11, -M10, -M09, -M08, -M07, -M06, -M05, -M04, -M03, -M02, -M01,
  -1.0f, -M01, -M02, -M03, -M04, -M05, -M06, -M07, -M08, -M09, -M10, -M11, -M12, -M13, -M14, -M15};

__device__ __forceinline__ void init_tw2(float2* tw, int t) {
  if (t < 64) {
    float s, c;
    sincosf(TWOPI_64 * (float)t, &s, &c);
    tw[t] = make_float2(c, s);
  }
}

// ============================ F23 ============================
// 256 thr = 4 waves; wave w owns plane = blockIdx*4 + w. Per-wave LDS slice.
__global__ __launch_bounds__(256) void k_f23(const float* __restrict__ x,
                                             float2* __restrict__ o) {
  __shared__ float2 Xs[4][1024];  // [wave][x2*16 + swizzled chunk*2 + sub]
  __shared__ float2 tw[64];
  const int t = threadIdx.x;
  const int lane = t & 63;
  const int w = t >> 6;
  const int plane = (blockIdx.x << 2) + w;
  init_tw2(tw, t);

  // ---- stage 1: real DFT x3 -> k3 in [0,16), all in registers ----
  const float4* xg = (const float4*)(x + (size_t)plane * 4096 + lane * 64);
  float r[64];
#pragma unroll
  for (int j = 0; j < 16; ++j) {
    float4 v = xg[j];
    r[4 * j] = v.x; r[4 * j + 1] = v.y; r[4 * j + 2] = v.z; r[4 * j + 3] = v.w;
  }
  // radix-4 pre-pass (x3 = 16a + b)
  float y0[16], y2[16], o0[16], o1[16];
#pragma unroll
  for (int b = 0; b < 16; ++b) {
    float d0 = r[b], d1 = r[16 + b], d2 = r[32 + b], d3 = r[48 + b];
    float e0 = d0 + d2, e1 = d1 + d3;
    o0[b] = d0 - d2; o1[b] = d1 - d3;
    y0[b] = e0 + e1; y2[b] = e0 - e1;
  }
  float4* Xw4 = (float4*)&Xs[w][lane * 16];  // lane's row, 8 16B chunks
#pragma unroll
  for (int c8 = 0; c8 < 8; ++c8) {
    const int k0 = 2 * c8, k1 = 2 * c8 + 1;  // k0 even, k1 odd
    float re0, im0, re1, im1;
    if ((k0 & 3) == 0) {
      re0 = y0[0]; im0 = 0.f;
#pragma unroll
      for (int b = 1; b < 16; ++b) {
        re0 = fmaf(y0[b], TC_H[(k0 * b) & 63], re0);
        im0 = fmaf(-y0[b], TS_H[(k0 * b) & 63], im0);
      }
    } else {
      re0 = y2[0]; im0 = 0.f;
#pragma unroll
      for (int b = 1; b < 16; ++b) {
        re0 = fmaf(y2[b], TC_H[(k0 * b) & 63], re0);
        im0 = fmaf(-y2[b], TS_H[(k0 * b) & 63], im0);
      }
    }
    if ((k1 & 3) == 1) {
      re1 = o0[0]; im1 = -o1[0];
#pragma unroll
      for (int b = 1; b < 16; ++b) {
        float c = TC_H[(k1 * b) & 63], s = TS_H[(k1 * b) & 63];
        re1 = fmaf(o0[b], c, re1); re1 = fmaf(-o1[b], s, re1);
        im1 = fmaf(-o0[b], s, im1); im1 = fmaf(-o1[b], c, im1);
      }
    } else {
      re1 = o0[0]; im1 = o1[0];
#pragma unroll
      for (int b = 1; b < 16; ++b) {
        float c = TC_H[(k1 * b) & 63], s = TS_H[(k1 * b) & 63];
        re1 = fmaf(o0[b], c, re1); re1 = fmaf(o1[b], s, re1);
        im1 = fmaf(o1[b], c, im1); im1 = fmaf(-o0[b], s, im1);
      }
    }
    Xw4[c8 ^ (lane & 7)] = make_float4(re0, im0, re1, im1);  // swizzled chunk
  }
  __syncthreads();  // tw table + own-wave LDS visibility

  // ---- stage 2: complex DFT x2 -> 32 modes ----
  // Radix-2 fold: B(k) = sum_{b<32} w(kb) [X(b) + (-1)^k X(b+32)].
  const int k3 = lane & 15, g = lane >> 4;
  float P[4] = {0, 0, 0, 0}, Q[4] = {0, 0, 0, 0};
  float R[4] = {0, 0, 0, 0}, S[4] = {0, 0, 0, 0};
  float A0 = 0.f, B0 = 0.f;
  const float ps = (g & 1) ? -1.f : 1.f;
  int kk[4], idx[4];
#pragma unroll
  for (int j = 0; j < 4; ++j) {
    int s = g + 4 * j;
    kk[j] = (s == 0) ? 48 : s;   // slot 0 handles mode 48 (even, ps=+1 ok)
    idx[j] = 0;
  }
  const float2* row = &Xs[w][0];
  const int sub = k3 & 1, ch = k3 >> 1;
#pragma unroll 8
  for (int b = 0; b < 32; ++b) {
    const int off = ((ch ^ (b & 7)) << 1) + sub;  // (b+32)&7 == b&7: same off
    float2 v1 = row[b * 16 + off];
    float2 v2 = row[(b + 32) * 16 + off];
    float2 par = make_float2(fmaf(ps, v2.x, v1.x), fmaf(ps, v2.y, v1.y));
#pragma unroll
    for (int j = 0; j < 4; ++j) {
      float2 wv = tw[idx[j]];
      idx[j] = (idx[j] + kk[j]) & 63;
      P[j] = fmaf(par.x, wv.x, P[j]); Q[j] = fmaf(par.y, wv.y, Q[j]);
      R[j] = fmaf(par.y, wv.x, R[j]); S[j] = fmaf(par.x, wv.y, S[j]);
    }
    A0 += par.x; B0 += par.y;  // g=0 (E-fold): mode 0 = sum_b E(b)
  }
  float2* ob = o + (size_t)plane * 512 + k3;
#pragma unroll
  for (int j = 0; j < 4; ++j) {
    int s = g + 4 * j;
    float2 oa = make_float2(P[j] + Q[j], R[j] - S[j]);
    if (s == 0) {
      ob[256] = oa;                    // mode 48 -> k2i=16
      ob[0] = make_float2(A0, B0);     // mode 0  -> k2i=0
    } else {
      ob[s * 16] = oa;                              // mode s -> k2i=s
      ob[(32 - s) * 16] = make_float2(P[j] - Q[j], R[j] + S[j]);  // 64-s
    }
  }
}

// ============================ F1 ============================
// per (bci,k2i). 512 thr. Radix-2 fold over x1 + PQRS conj-pair, k3-paired.
__global__ __launch_bounds__(512) void k_f1(const float2* __restrict__ in,
                                            float2* __restrict__ o) {
  __shared__ float2 xsf[64 * 18];
  __shared__ float4 red[2][512];
  __shared__ float4 redAB[32];
  __shared__ float2 tw[64];
  const int t = threadIdx.x;
  init_tw2(tw, t);
  const int bci = blockIdx.x >> 5, k2i = blockIdx.x & 31;
  {
    int x1 = t >> 3, k3p = t & 7;
    float4 v = ((const float4*)in)[((size_t)(bci * 64 + x1) * 32 + k2i) * 8 + k3p];
    *(float4*)&xsf[x1 * 18 + 2 * k3p] = v;
  }
  __syncthreads();
  {
    const int k3p = t & 7, slot = (t >> 3) & 15, h = t >> 7;  // h in [0,4)
    const bool isz = (slot == 0);
    const int kk = isz ? 48 : slot;
    const float ps = (slot & 1) ? -1.f : 1.f;  // slot0: kk=48 even, ps=+1 ok
    float Pa=0,Qa=0,Ra=0,Sa=0, Pb=0,Qb=0,Rb=0,Sb=0, Aa=0,Ba=0,Ab=0,Bb=0;
    int idx = (kk * 8 * h) & 63;
#pragma unroll
    for (int i = 0; i < 8; ++i) {
      int b = 8 * h + i;  // b in [0,32): fold (b, b+32)
      float4 v1 = *(const float4*)&xsf[b * 18 + 2 * k3p];
      float4 v2 = *(const float4*)&xsf[(b + 32) * 18 + 2 * k3p];
      float4 par;
      par.x = fmaf(ps, v2.x, v1.x); par.y = fmaf(ps, v2.y, v1.y);
      par.z = fmaf(ps, v2.z, v1.z); par.w = fmaf(ps, v2.w, v1.w);
      float2 w = tw[idx]; idx = (idx + kk) & 63;
      Pa = fmaf(par.x, w.x, Pa); Qa = fmaf(par.y, w.y, Qa);
      Ra = fmaf(par.y, w.x, Ra); Sa = fmaf(par.x, w.y, Sa);
      Pb = fmaf(par.z, w.x, Pb); Qb = fmaf(par.w, w.y, Qb);
      Rb = fmaf(par.w, w.x, Rb); Sb = fmaf(par.z, w.y, Sb);
      if (isz) { Aa += par.x; Ba += par.y; Ab += par.z; Bb += par.w; }
    }
    red[0][k3p + 8 * slot + 128 * h] = make_float4(Pa, Qa, Ra, Sa);
    red[1][k3p + 8 * slot + 128 * h] = make_float4(Pb, Qb, Rb, Sb);
    if (isz) redAB[8 * h + k3p] = make_float4(Aa, Ba, Ab, Bb);
  }
  __syncthreads();
  if (t < 256) {
    const int slot = t >> 4, k3 = t & 15, k3p = k3 >> 1, half = k3 & 1;
    int b = k3p + 8 * slot;
    float4 s0 = red[half][b], s1 = red[half][b + 128];
    float4 s2 = red[half][b + 256], s3 = red[half][b + 384];
    float P = s0.x + s1.x + s2.x + s3.x, Q = s0.y + s1.y + s2.y + s3.y;
    float R = s0.z + s1.z + s2.z + s3.z, S = s0.w + s1.w + s2.w + s3.w;
    float2 oa = make_float2(P + Q, R - S);
    float2 ob; int ka, kb;
    if (slot == 0) {
      ka = 16; kb = 0;
      const float2* ab = (const float2*)redAB;
      float2 z0 = ab[(0 * 8 + k3p) * 2 + half], z1 = ab[(1 * 8 + k3p) * 2 + half];
      float2 z2 = ab[(2 * 8 + k3p) * 2 + half], z3 = ab[(3 * 8 + k3p) * 2 + half];
      ob = make_float2(z0.x + z1.x + z2.x + z3.x, z0.y + z1.y + z2.y + z3.y);
    } else {
      ka = slot; kb = 32 - slot;
      ob = make_float2(P - Q, R + S);
    }
    o[(((size_t)bci * 32 + ka) * 32 + k2i) * 16 + k3] = oa;
    o[(((size_t)bci * 32 + kb) * 32 + k2i) * 16 + k3] = ob;
  }
}

// ============================ MIX ============================
__global__ __launch_bounds__(512) void k_mix(const float2* __restrict__ X,
                                             const float2* __restrict__ w0,
                                             const float2* __restrict__ w1,
                                             const float2* __restrict__ w2,
                                             const float2* __restrict__ w3,
                                             float2* __restrict__ Y) {
  __shared__ float2 xs[2048];  // [b*32+ci][k3]
  const int t = threadIdx.x;
  const int k1i = blockIdx.x >> 5, k2i = blockIdx.x & 31;
  const float2* w = (k1i < 16) ? ((k2i < 16) ? w0 : w1) : ((k2i < 16) ? w2 : w3);
  const int a = k1i & 15, bb = k2i & 15;
  for (int q = t; q < 2048; q += 512) {
    int bci = q >> 4, k3 = q & 15;
    xs[q] = X[((size_t)bci * 1024 + blockIdx.x) * 16 + k3];
  }
  __syncthreads();
  const int k3 = t & 15, co = t >> 4;
  float2 a0 = {0, 0}, a1 = {0, 0}, a2 = {0, 0}, a3 = {0, 0};
  const float2* wp = w + (size_t)co * 4096 + a * 256 + bb * 16 + k3;
#pragma unroll 16
  for (int ci = 0; ci < 32; ++ci) {
    float2 wv = wp[(size_t)ci * 131072];
    float2 x0 = xs[(0 * 32 + ci) * 16 + k3];
    float2 x1 = xs[(1 * 32 + ci) * 16 + k3];
    float2 x2 = xs[(2 * 32 + ci) * 16 + k3];
    float2 x3 = xs[(3 * 32 + ci) * 16 + k3];
    a0.x = fmaf(x0.x, wv.x, a0.x); a0.x = fmaf(-x0.y, wv.y, a0.x);
    a0.y = fmaf(x0.x, wv.y, a0.y); a0.y = fmaf(x0.y, wv.x, a0.y);
    a1.x = fmaf(x1.x, wv.x, a1.x); a1.x = fmaf(-x1.y, wv.y, a1.x);
    a1.y = fmaf(x1.x, wv.y, a1.y); a1.y = fmaf(x1.y, wv.x, a1.y);
    a2.x = fmaf(x2.x, wv.x, a2.x); a2.x = fmaf(-x2.y, wv.y, a2.x);
    a2.y = fmaf(x2.x, wv.y, a2.y); a2.y = fmaf(x2.y, wv.x, a2.y);
    a3.x = fmaf(x3.x, wv.x, a3.x); a3.x = fmaf(-x3.y, wv.y, a3.x);
    a3.y = fmaf(x3.x, wv.y, a3.y); a3.y = fmaf(x3.y, wv.x, a3.y);
  }
  const float nrm = 1.0f / 262144.0f;  // 1/64^3
  Y[((size_t)(0 * 32 + co) * 1024 + blockIdx.x) * 16 + k3] = make_float2(a0.x * nrm, a0.y * nrm);
  Y[((size_t)(1 * 32 + co) * 1024 + blockIdx.x) * 16 + k3] = make_float2(a1.x * nrm, a1.y * nrm);
  Y[((size_t)(2 * 32 + co) * 1024 + blockIdx.x) * 16 + k3] = make_float2(a2.x * nrm, a2.y * nrm);
  Y[((size_t)(3 * 32 + co) * 1024 + blockIdx.x) * 16 + k3] = make_float2(a3.x * nrm, a3.y * nrm);
}

// ============================ I1 ============================
// per (bco,k2i). 256 thr: k3 = t&15, x1 = t>>4 in [0,16).
// 4-way phase-class fold: G_c = sum_{i==c mod 4} z_i w+(k_i x1);
// out(x1+16q) = sum_c i^{cq} G_c.
__global__ __launch_bounds__(256) void k_i1(const float2* __restrict__ Y,
                                            float2* __restrict__ o) {
  __shared__ float2 zs[32 * 18];
  __shared__ float2 tw[64];
  const int t = threadIdx.x;
  init_tw2(tw, t);
  const int bco = blockIdx.x >> 5, k2i = blockIdx.x & 31;
  {
    int k1i = t >> 3, k3p = t & 7;
    float4 v = ((const float4*)Y)[((size_t)(bco * 32 + k1i) * 32 + k2i) * 8 + k3p];
    *(float4*)&zs[k1i * 18 + 2 * k3p] = v;
  }
  __syncthreads();
  const int k3 = t & 15, x1 = t >> 4;  // x1 in [0,16)
  float Gr[4] = {0, 0, 0, 0}, Gi[4] = {0, 0, 0, 0};
#pragma unroll
  for (int i = 0; i < 32; ++i) {
    const int k = i + ((i >= 16) ? 32 : 0);  // compile-time
    const int c = i & 3;
    float2 z = zs[i * 18 + k3];
    float2 w = tw[(k * x1) & 63];
    Gr[c] = fmaf(z.x, w.x, Gr[c]); Gr[c] = fmaf(-z.y, w.y, Gr[c]);
    Gi[c] = fmaf(z.y, w.x, Gi[c]); Gi[c] = fmaf(z.x, w.y, Gi[c]);
  }
  const float Ar = Gr[0] + Gr[2], Ai = Gi[0] + Gi[2];
  const float Br = Gr[1] + Gr[3], Bi = Gi[1] + Gi[3];
  const float Cr = Gr[0] - Gr[2], Ci = Gi[0] - Gi[2];
  const float Dr = Gr[1] - Gr[3], Di = Gi[1] - Gi[3];
  const size_t base = ((size_t)(bco * 64 + x1) * 32 + k2i) * 16 + k3;
  const size_t st = (size_t)16 * 512;  // x1 += 16
  o[base]          = make_float2(Ar + Br, Ai + Bi);  // q=0
  o[base + st]     = make_float2(Cr - Di, Ci + Dr);  // q=1: C + iD
  o[base + 2 * st] = make_float2(Ar - Br, Ai - Bi);  // q=2
  o[base + 3 * st] = make_float2(Cr + Di, Ci - Dr);  // q=3: C - iD
}

// ============================ I23 ============================
// TWO planes per 512-thr block: half hp = t>>8 owns plane blockIdx*2+hp.
// Stage A (256 thr/plane): inverse k2->x2 via 4-way phase-class fold
// (x2 in [0,16), k3 in [0,16); out(x2+16q) = sum_c i^cq G_c).
// Stage B (256 thr/plane): irfft k3->x3, 4-way x3 tiling via i^k trick.
__global__ __launch_bounds__(512) void k_i23(const float2* __restrict__ Z1,
                                             float* __restrict__ out) {
  __shared__ float2 zs[2][32 * 18];  // [plane][k2i][k3] pad-18
  __shared__ float2 Zc[2][64 * 18];  // [plane][x2][k3] pad-18, Hermitian 2x
  __shared__ float2 tw[64];
  const int t = threadIdx.x;
  init_tw2(tw, t);
  const int hp = t >> 8;       // which plane of the pair
  const int u = t & 255;       // index within the half
  const size_t plane = (size_t)blockIdx.x * 2 + hp;
  {
    int k2i = u >> 3, k3p = u & 7;
    float4 v = ((const float4*)(Z1 + plane * 512))[u];
    *(float4*)&zs[hp][k2i * 18 + 2 * k3p] = v;
  }
  __syncthreads();
  {  // stage A: 4-way phase-class inverse DFT k2 -> x2
    const int k3 = u & 15, x2 = u >> 4;  // x2 in [0,16)
    float Gr[4] = {0, 0, 0, 0}, Gi[4] = {0, 0, 0, 0};
#pragma unroll
    for (int i = 0; i < 32; ++i) {
      const int k = i + ((i >= 16) ? 32 : 0);  // compile-time
      const int c = i & 3;
      float2 z = zs[hp][i * 18 + k3];
      float2 w = tw[(k * x2) & 63];
      Gr[c] = fmaf(z.x, w.x, Gr[c]); Gr[c] = fmaf(-z.y, w.y, Gr[c]);
      Gi[c] = fmaf(z.y, w.x, Gi[c]); Gi[c] = fmaf(z.x, w.y, Gi[c]);
    }
    const float Ar = Gr[0] + Gr[2], Ai = Gi[0] + Gi[2];
    const float Br = Gr[1] + Gr[3], Bi = Gi[1] + Gi[3];
    const float Cr = Gr[0] - Gr[2], Ci = Gi[0] - Gi[2];
    const float Dr = Gr[1] - Gr[3], Di = Gi[1] - Gi[3];
    const float sc = (k3 == 0) ? 1.f : 2.f;  // Hermitian double-count, k3>0
    Zc[hp][(x2)*18 + k3]      = make_float2(sc * (Ar + Br), sc * (Ai + Bi));
    Zc[hp][(x2 + 16)*18 + k3] = make_float2(sc * (Cr - Di), sc * (Ci + Dr));
    Zc[hp][(x2 + 32)*18 + k3] = make_float2(sc * (Ar - Br), sc * (Ai - Bi));
    Zc[hp][(x2 + 48)*18 + k3] = make_float2(sc * (Cr + Di), sc * (Ci - Dr));
  }
  __syncthreads();
  // stage B: out(x3b+16m) = sum_k Re(z_k w(k*x3b) i^{km}); 4 x2-rows/thread
  {
    const int x3b = u & 15, x2g = u >> 4;  // x2g in [0,16)
    float2 wk[16];
    int idx = 0;
#pragma unroll
    for (int k = 0; k < 16; ++k) { wk[k] = tw[idx]; idx = (idx + x3b) & 63; }
    float* ob = out + plane * 4096;
#pragma unroll
    for (int rr = 0; rr < 4; ++rr) {
      int x2 = x2g + 16 * rr;
      const float4* zp = (const float4*)&Zc[hp][x2 * 18];
      float Sa0=0, Sa1=0, Sa2=0, Sa3=0, Sb1=0, Sb3=0;
#pragma unroll
      for (int j = 0; j < 8; ++j) {
        float4 z = zp[j];  // cplx 2j (x,y) and 2j+1 (z,w)
        float2 we = wk[2 * j], wo = wk[2 * j + 1];
        if ((j & 1) == 0) {
          Sa0 = fmaf(z.x, we.x, Sa0); Sa0 = fmaf(-z.y, we.y, Sa0);
          Sa1 = fmaf(z.z, wo.x, Sa1); Sa1 = fmaf(-z.w, wo.y, Sa1);
          Sb1 = fmaf(z.z, wo.y, Sb1); Sb1 = fmaf(z.w, wo.x, Sb1);
        } else {
          Sa2 = fmaf(z.x, we.x, Sa2); Sa2 = fmaf(-z.y, we.y, Sa2);
          Sa3 = fmaf(z.z, wo.x, Sa3); Sa3 = fmaf(-z.w, wo.y, Sa3);
          Sb3 = fmaf(z.z, wo.y, Sb3); Sb3 = fmaf(z.w, wo.x, Sb3);
        }
      }
      ob[x2 * 64 + x3b]      = Sa0 + Sa1 + Sa2 + Sa3;
      ob[x2 * 64 + x3b + 16] = Sa0 - Sb1 - Sa2 + Sb3;
      ob[x2 * 64 + x3b + 32] = Sa0 - Sa1 + Sa2 - Sa3;
      ob[x2 * 64 + x3b + 48] = Sa0 + Sb1 - Sa2 - Sb3;
    }
  }
}

extern "C" void kernel_launch(void* const* d_in, const int* in_sizes, int n_in,
                              void* d_out, int out_size, void* d_ws, size_t ws_size,
                              hipStream_t stream) {
  (void)in_sizes; (void)n_in; (void)out_size; (void)ws_size;
  const float* x = (const float*)d_in[0];
  const float2* w0 = (const float2*)d_in[1];
  const float2* w1 = (const float2*)d_in[2];
  const float2* w2 = (const float2*)d_in[3];
  const float2* w3 = (const float2*)d_in[4];
  float* out = (float*)d_out;
  char* ws = (char*)d_ws;

  // Workspace (67,108,864 B):
  //  B1 = ws[0 : 33.5MB)    f23 out; dead after f1 -> reused as B2 (i1 out)
  //  C  = ws[33.5 : 50.3MB) f1 out
  //  D  = ws[50.3 : 67.1MB) mix out
  float2* B1 = (float2*)ws;
  float2* C  = (float2*)(ws + 33554432);
  float2* D  = (float2*)(ws + 50331648);
  float2* B2 = B1;

  k_f23<<<2048, 256, 0, stream>>>(x, B1);
  k_f1 <<<4096, 512, 0, stream>>>(B1, C);
  k_mix<<<1024, 512, 0, stream>>>(C, w0, w1, w2, w3, D);
  k_i1 <<<4096, 256, 0, stream>>>(D, B2);
  k_i23<<<4096, 512, 0, stream>>>(B2, out);
}